// Round 3
// baseline (149.709 us; speedup 1.0000x reference)
//
#include <hip/hip_runtime.h>
#include <hip/hip_bf16.h>
#include <hip/hip_fp16.h>

// Sparse gather-FFN, DS-pipe bound. Verified model (R15 counters): per CU
// 8192 wave ds_read_b128 x 12cyc = 41us issue floor + conflict cycles
// (SQ_LDS_BANK_CONFLICT/256/2.4GHz). R15: sort-by-bank-group + spaced-2
// rotation (phase = 8 consecutive lanes, 8x16B = all 32 banks) ->
// conflicts 1.66e7 -> 1.494e7, main 67us = 41 + 24(conflict) + 2.
// R16: kill the remaining conflicts. Residual cause: per-lane multinomial
// (16,8) group-count variance misaligns sorted-position->group boundaries
// across lanes. Fix: store EVERY value twice - copy0 at f*16 (group f&7),
// copy1 at C1OFF+16+f*16 (group (f+1)&7). Each item now has a 2-choice of
// bank group on a cycle; prepass runs a cycle-transport pass to flatten
// each lane's histogram to ~(2,2,...,2), then sort+rotate as before ->
// phases hit 8 distinct groups -> near-zero conflicts.
// LDS doubles -> RPB=8 (reads/row invariant), 60.0KB, still 2 blocks/CU.
// Predicted: SQ_LDS_BANK_CONFLICT 1.494e7 -> 3-6e6, main 67 -> 52-57us.

#define NB   32768
#define NIN  128
#define NL   8
#define NW   256
#define NK   16
#define RPB  8                        // rows per block (one 8-row group)
#define STORED (NIN + (NL - 1) * NW)  // 1920 features
#define NPARAM (NL * NW * NK)         // 32768 (l,u,k) entries
#define C1OFF  (STORED * 16)          // 30720: replica region base
#define LDSBYTES (C1OFF + 16 + STORED * 16)  // 61456 (copy1 shifted +16B)

typedef __fp16 fp16v2 __attribute__((ext_vector_type(2)));
typedef unsigned long long u64;

__device__ __forceinline__ unsigned pk16(float a, float b) {
    fp16v2 p = __builtin_amdgcn_cvt_pkrtz(a, b);   // v_cvt_pkrtz_f16_f32
    return __builtin_bit_cast(unsigned, p);
}

__device__ __forceinline__ __half2 as_h2(unsigned u) {
    return __builtin_bit_cast(__half2, u);
}

__device__ __forceinline__ float fast_sigmoid(float x) {
    return __builtin_amdgcn_rcpf(1.0f + __expf(-x));
}

// 8 row-MACs from one 16B packed-f16 word: 4x v_pk_fma_f16
__device__ __forceinline__ void fma_feat(__half2 acc[4], __half2 w2, uint4 p) {
    acc[0] = __hfma2(as_h2(p.x), w2, acc[0]);
    acc[1] = __hfma2(as_h2(p.y), w2, acc[1]);
    acc[2] = __hfma2(as_h2(p.z), w2, acc[2]);
    acc[3] = __hfma2(as_h2(p.w), w2, acc[3]);
}

template <bool PRE>
__global__ __launch_bounds__(256, 2)
void ffn_gather_kernel(const float* __restrict__ inputs,
                       const float* __restrict__ weights,
                       const float* __restrict__ biases,
                       const int*   __restrict__ edge_idx,
                       const int*   __restrict__ idxb,   // absolute byte offs
                       const unsigned* __restrict__ wpk, // packed (w,w) f16
                       float* __restrict__ out)
{
    __shared__ __align__(16) char vals[LDSBYTES];

    const int t = threadIdx.x;                       // 0..255, unit id
    const long long row0 = (long long)blockIdx.x * RPB;

    // ---- stage 128 input features x 8 rows into BOTH copies ----
    // t<128 -> copy0 at f*16; t>=128 -> copy1 at C1OFF+16+f*16 (dup loads
    // hit L1; two writers to disjoint addresses).
    {
        const int f = t & 127;
        float v[8];
        #pragma unroll
        for (int r = 0; r < 8; ++r) v[r] = inputs[(row0 + r) * NIN + f];
        uint4 p;
        p.x = pk16(v[0], v[1]);
        p.y = pk16(v[2], v[3]);
        p.z = pk16(v[4], v[5]);
        p.w = pk16(v[6], v[7]);
        *(uint4*)(vals + ((t >> 7) ? (C1OFF + 16 + f * 16) : (f * 16))) = p;
    }
    __syncthreads();

    // ---- layers ----
    #pragma unroll
    for (int l = 0; l < NL; ++l) {
        const int base = (l * NW + t) * NK;

        const float b = biases[l * NW + t];
        __half2 acc[4];
        const __half2 bb = __float2half2_rn(b);
        #pragma unroll
        for (int j = 0; j < 4; ++j) acc[j] = bb;

        #pragma unroll
        for (int kk = 0; kk < NK / 4; ++kk) {
            int4 o4;
            __half2 w0, w1, w2, w3;
            if (PRE) {
                o4 = ((const int4*)(idxb + base))[kk];   // absolute byte offs
                uint4 wp = ((const uint4*)(wpk + base))[kk];
                w0 = as_h2(wp.x); w1 = as_h2(wp.y);
                w2 = as_h2(wp.z); w3 = as_h2(wp.w);
            } else {
                int4 i4 = ((const int4*)(edge_idx + base))[kk];
                o4.x = i4.x << 4; o4.y = i4.y << 4;   // copy0 only
                o4.z = i4.z << 4; o4.w = i4.w << 4;
                float4 w4 = ((const float4*)(weights + base))[kk];
                w0 = __float2half2_rn(w4.x);
                w1 = __float2half2_rn(w4.y);
                w2 = __float2half2_rn(w4.z);
                w3 = __float2half2_rn(w4.w);
            }
            const uint4 a0 = *(const uint4*)(vals + o4.x);
            const uint4 a1 = *(const uint4*)(vals + o4.y);
            const uint4 a2 = *(const uint4*)(vals + o4.z);
            const uint4 a3 = *(const uint4*)(vals + o4.w);
            fma_feat(acc, w0, a0);
            fma_feat(acc, w1, a1);
            fma_feat(acc, w2, a2);
            fma_feat(acc, w3, a3);
        }

        float s[8];
        #pragma unroll
        for (int j = 0; j < 4; ++j) {
            s[2 * j + 0] = fast_sigmoid(__low2float(acc[j]));
            s[2 * j + 1] = fast_sigmoid(__high2float(acc[j]));
        }

        if (l < NL - 1) {
            uint4 p;
            p.x = pk16(s[0], s[1]); p.y = pk16(s[2], s[3]);
            p.z = pk16(s[4], s[5]); p.w = pk16(s[6], s[7]);
            const int F = NIN + l * NW + t;
            *(uint4*)(vals + F * 16) = p;                  // copy0
            *(uint4*)(vals + C1OFF + 16 + F * 16) = p;     // copy1 (+16B)
            __syncthreads();
        } else {
            #pragma unroll
            for (int r = 0; r < 8; ++r)
                out[(row0 + r) * NW + t] = s[r];
        }
    }
}

// R16 prepass. Per unit (l*NW+u), lane = u&63:
// 1. counts cnt[g] of bank group g = idx&7 (packed u64 bytes).
// 2. cycle-transport: s[g] = #items shifting g -> g+1 (read replica copy1,
//    group +1), fixed-point s[g] = clamp(s[g-1]+cnt[g]-2, 0, cnt[g]),
//    3 sweeps -> per-lane final histogram ~= (2,...,2) when feasible.
// 3. counting-sort by FINAL group + spaced-2 rotation (R15):
//    rot = (2*(lane&7) + (lane>>3)) & 15 -> 8 consecutive lanes read 8
//    distinct groups when histograms are uniform -> ~zero conflicts.
// idxb stores ABSOLUTE byte offsets (copy0: idx*16; copy1: C1OFF+16+idx*16).
// All packed-u64 state, no runtime-indexed arrays (scratch rule).
__global__ __launch_bounds__(256)
void balance_prepass_kernel(const float* __restrict__ weights,
                            const int* __restrict__ edge_idx,
                            int* __restrict__ idxb,
                            unsigned* __restrict__ wpk)
{
    const int t = blockIdx.x * 256 + threadIdx.x;   // 0..2047: unit (l*NW+u)
    const int lane = t & 63;                        // main-kernel wave lane
    const int base = t * NK;

    int   idxv[NK];
    float wv[NK];
    #pragma unroll
    for (int j = 0; j < NK; ++j) {
        idxv[j] = edge_idx[base + j];
        wv[j]   = weights[base + j];
    }

    u64 cntp = 0;
    #pragma unroll
    for (int j = 0; j < NK; ++j)
        cntp += 1ull << ((idxv[j] & 7) * 8);

    // shift counts s[g] (packed bytes), 3 relaxation sweeps around the cycle
    u64 s_pk = 0;
    #pragma unroll
    for (int it = 0; it < 3; ++it) {
        #pragma unroll
        for (int g = 0; g < 8; ++g) {
            const int gp = (g + 7) & 7;
            int sp = (int)((s_pk >> (gp * 8)) & 0xFF);
            int c  = (int)((cntp >> (g * 8)) & 0xFF);
            int v  = sp + c - 2;
            v = v < 0 ? 0 : (v > c ? c : v);
            s_pk = (s_pk & ~(0xFFull << (g * 8))) | ((u64)v << (g * 8));
        }
    }
    const u64 keep_pk = cntp - s_pk;   // bytewise ok: s[g] <= cnt[g]

    // per-item shift decision: within group g, first keep_pk[g] items stay
    u64 used = 0;
    int fg[NK], sh[NK];
    #pragma unroll
    for (int j = 0; j < NK; ++j) {
        const int g  = idxv[j] & 7;
        const int u_ = (int)((used >> (g * 8)) & 0xFF);
        used += 1ull << (g * 8);
        const int kp = (int)((keep_pk >> (g * 8)) & 0xFF);
        sh[j] = (u_ >= kp) ? 1 : 0;
        fg[j] = (g + sh[j]) & 7;
    }

    // counting sort by final group
    u64 fcnt = 0;
    #pragma unroll
    for (int j = 0; j < NK; ++j)
        fcnt += 1ull << (fg[j] * 8);

    u64 x = fcnt;                 // per-byte inclusive prefix sum
    x += x << 8;
    x += x << 16;
    x += x << 32;
    u64 cur = x << 8;             // exclusive

    const int rot = (2 * (lane & 7) + ((lane >> 3) & 7)) & 15;
    #pragma unroll
    for (int j = 0; j < NK; ++j) {
        const int g   = fg[j];
        const int pos = (int)((cur >> (g * 8)) & 0xFF);   // unique 0..15
        cur += 1ull << (g * 8);
        const int slot = (pos + rot) & 15;
        idxb[base + slot] = sh[j] ? (C1OFF + 16 + (idxv[j] << 4))
                                  : (idxv[j] << 4);
        wpk [base + slot] = pk16(wv[j], wv[j]);
    }
}

extern "C" void kernel_launch(void* const* d_in, const int* in_sizes, int n_in,
                              void* d_out, int out_size, void* d_ws, size_t ws_size,
                              hipStream_t stream)
{
    const float* inputs   = (const float*)d_in[0];
    const float* weights  = (const float*)d_in[1];
    const float* biases   = (const float*)d_in[2];
    const int*   edge_idx = (const int*)d_in[3];
    float* out = (float*)d_out;

    dim3 grid(NB / RPB);   // 4096
    dim3 block(NW);        // 256

    const size_t need = (size_t)NPARAM * 4 * 2;     // 256 KB
    if (ws_size >= need) {
        int*      idxb = (int*)d_ws;
        unsigned* wpk  = (unsigned*)((char*)d_ws + (size_t)NPARAM * 4);
        balance_prepass_kernel<<<NL * NW / 256, 256, 0, stream>>>(
            weights, edge_idx, idxb, wpk);
        ffn_gather_kernel<true><<<grid, block, 0, stream>>>(
            inputs, weights, biases, edge_idx, idxb, wpk, out);
    } else {
        ffn_gather_kernel<false><<<grid, block, 0, stream>>>(
            inputs, weights, biases, edge_idx, nullptr, nullptr, out);
    }
}

// Round 4
// 146.238 us; speedup vs baseline: 1.0237x; 1.0237x over previous
//
#include <hip/hip_runtime.h>
#include <hip/hip_bf16.h>
#include <hip/hip_fp16.h>

// Sparse gather-FFN, DS-pipe bound. Verified model: per CU 8192 wave
// ds_read_b128 x 12cyc = 41us issue floor + conflict cycles
// (SQ_LDS_BANK_CONFLICT/256/2.4GHz).
// History: R13 RPB=16 dual-group 67us shell. R14 bad rotation: conflicts
// 2.20e7 (phases = consecutive lanes). R15 sort+spaced-2 rot: 1.494e7,
// main 67us = 41+24+2. R16 per-lane +1-cyclic replica + RPB=8: conflicts
// only 1.334e7 and main 83.5us (RPB=8 doubled staging/tail overhead,
// +18us). Post-mortem: per-OCTET group-demand excess is an ordering-
// independent floor: demand[g] = sum over 8 lanes of cnt[g] ~ 16+-3.74;
// excess over 16 serializes regardless of slot order ~= 6/instr = the
// measured 6.36. Ordering is solved; DEMAND variance is the bottleneck.
// R17: revert to R15 shell (RPB=16, no replica). Prepass partitions the
// 256 units of each layer into 32 octets with balanced summed histograms
// (latin deal by argmax-group rank within residue class; u mod 8 kept
// invariant so remapped feature ids keep their bank group -> layers stay
// independent). Indices remapped in prepass; main gather loop IDENTICAL
// to R15. Only bias (via punit gather) + out column change.
// Predicted: conflicts 1.334e7 -> 7-10e6, main -> 55-60us.

#define NB   32768
#define NIN  128
#define NL   8
#define NW   256
#define NK   16
#define RPB  16                       // rows per block = 2 groups x 8
#define STORED (NIN + (NL - 1) * NW)  // 1920 features per group
#define NPARAM (NL * NW * NK)         // 32768 (l,u,k) entries

typedef __fp16 fp16v2 __attribute__((ext_vector_type(2)));
typedef unsigned long long u64;

__device__ __forceinline__ unsigned pk16(float a, float b) {
    fp16v2 p = __builtin_amdgcn_cvt_pkrtz(a, b);   // v_cvt_pkrtz_f16_f32
    return __builtin_bit_cast(unsigned, p);
}

__device__ __forceinline__ __half2 as_h2(unsigned u) {
    return __builtin_bit_cast(__half2, u);
}

__device__ __forceinline__ float fast_sigmoid(float x) {
    return __builtin_amdgcn_rcpf(1.0f + __expf(-x));
}

// 8 row-MACs from one 16B packed-f16 word: 4x v_pk_fma_f16
__device__ __forceinline__ void fma_feat(__half2 acc[4], __half2 w2, uint4 p) {
    acc[0] = __hfma2(as_h2(p.x), w2, acc[0]);
    acc[1] = __hfma2(as_h2(p.y), w2, acc[1]);
    acc[2] = __hfma2(as_h2(p.z), w2, acc[2]);
    acc[3] = __hfma2(as_h2(p.w), w2, acc[3]);
}

template <bool PRE, bool PERM>
__global__ __launch_bounds__(256, 2)
void ffn_gather_kernel(const float* __restrict__ inputs,
                       const float* __restrict__ weights,
                       const float* __restrict__ biases,
                       const int*   __restrict__ edge_idx,
                       const int*   __restrict__ idxb,   // pre-scaled byte offs
                       const unsigned* __restrict__ wpk, // packed (w,w) f16
                       const int*   __restrict__ punit,  // (l,t) -> unit u
                       float* __restrict__ out)
{
    __shared__ uint4 valsA[STORED];   // group A: rows row0..row0+7
    __shared__ uint4 valsB[STORED];   // group B: rows row0+8..row0+15

    const int t = threadIdx.x;                       // 0..255, thread slot
    const long long row0 = (long long)blockIdx.x * RPB;
    const char* vbaseA = (const char*)valsA;
    const char* vbaseB = (const char*)valsB;

    // ---- stage 128 input features x 16 rows: t<128 -> A, t>=128 -> B ----
    {
        const int f = t & 127;
        const long long r0 = row0 + ((t >> 7) << 3);   // +0 (A) or +8 (B)
        float v[8];
        #pragma unroll
        for (int r = 0; r < 8; ++r) v[r] = inputs[(r0 + r) * NIN + f];
        uint4 p;
        p.x = pk16(v[0], v[1]);
        p.y = pk16(v[2], v[3]);
        p.z = pk16(v[4], v[5]);
        p.w = pk16(v[6], v[7]);
        if (t < NIN) valsA[f] = p; else valsB[f] = p;
    }
    __syncthreads();

    // ---- layers ----
    #pragma unroll
    for (int l = 0; l < NL; ++l) {
        const int base = (l * NW + t) * NK;

        // unit this thread computes (identity unless PERM)
        const int u = PERM ? punit[l * NW + t] : t;
        const float b = biases[l * NW + u];
        __half2 accA[4], accB[4];
        const __half2 bb = __float2half2_rn(b);
        #pragma unroll
        for (int j = 0; j < 4; ++j) { accA[j] = bb; accB[j] = bb; }

        #pragma unroll
        for (int kk = 0; kk < NK / 4; ++kk) {
            int4 o4;          // byte offsets into vals (shared by A and B!)
            __half2 w0, w1, w2, w3;
            if (PRE) {
                o4 = ((const int4*)(idxb + base))[kk];
                uint4 wp = ((const uint4*)(wpk + base))[kk];
                w0 = as_h2(wp.x); w1 = as_h2(wp.y);
                w2 = as_h2(wp.z); w3 = as_h2(wp.w);
            } else {
                int4 i4 = ((const int4*)(edge_idx + base))[kk];
                o4.x = i4.x << 4; o4.y = i4.y << 4;
                o4.z = i4.z << 4; o4.w = i4.w << 4;
                float4 w4 = ((const float4*)(weights + base))[kk];
                w0 = __float2half2_rn(w4.x);
                w1 = __float2half2_rn(w4.y);
                w2 = __float2half2_rn(w4.z);
                w3 = __float2half2_rn(w4.w);
            }
            // 8 independent gathers (two per feature, groups A+B)
            const uint4 a0 = *(const uint4*)(vbaseA + o4.x);
            const uint4 b0 = *(const uint4*)(vbaseB + o4.x);
            const uint4 a1 = *(const uint4*)(vbaseA + o4.y);
            const uint4 b1 = *(const uint4*)(vbaseB + o4.y);
            const uint4 a2 = *(const uint4*)(vbaseA + o4.z);
            const uint4 b2 = *(const uint4*)(vbaseB + o4.z);
            const uint4 a3 = *(const uint4*)(vbaseA + o4.w);
            const uint4 b3 = *(const uint4*)(vbaseB + o4.w);
            fma_feat(accA, w0, a0);
            fma_feat(accB, w0, b0);
            fma_feat(accA, w1, a1);
            fma_feat(accB, w1, b1);
            fma_feat(accA, w2, a2);
            fma_feat(accB, w2, b2);
            fma_feat(accA, w3, a3);
            fma_feat(accB, w3, b3);
        }

        float sA[8], sB[8];
        #pragma unroll
        for (int j = 0; j < 4; ++j) {
            sA[2 * j + 0] = fast_sigmoid(__low2float(accA[j]));
            sA[2 * j + 1] = fast_sigmoid(__high2float(accA[j]));
            sB[2 * j + 0] = fast_sigmoid(__low2float(accB[j]));
            sB[2 * j + 1] = fast_sigmoid(__high2float(accB[j]));
        }

        if (l < NL - 1) {
            uint4 pA, pB;
            pA.x = pk16(sA[0], sA[1]); pA.y = pk16(sA[2], sA[3]);
            pA.z = pk16(sA[4], sA[5]); pA.w = pk16(sA[6], sA[7]);
            pB.x = pk16(sB[0], sB[1]); pB.y = pk16(sB[2], sB[3]);
            pB.z = pk16(sB[4], sB[5]); pB.w = pk16(sB[6], sB[7]);
            // activation lives at THREAD slot (remap is in the indices)
            valsA[NIN + l * NW + t] = pA;
            valsB[NIN + l * NW + t] = pB;
            __syncthreads();           // ONE barrier per 16 rows per layer
        } else {
            #pragma unroll
            for (int r = 0; r < 8; ++r) {
                out[(row0 + r) * NW + u]     = sA[r];
                out[(row0 + 8 + r) * NW + u] = sB[r];
            }
        }
    }
}

// ---- P1: per-layer unit->lane partition (8 blocks x 256 threads) ----
// Class r = u&7 must keep its residue (octet position r) so remapped
// feature ids keep bank group (idx&7 invariant). Within each class, rank
// units by argmax bank-group (tiebreak u) and latin-deal rank j -> octet
// (j + 4r) & 31: each octet receives one unit peaked at each group ->
// summed octet histogram ~ (16,...,16), demand variance way down.
__global__ __launch_bounds__(256)
void partition_kernel(const int* __restrict__ edge_idx,
                      int* __restrict__ t_of,    // (l,u) -> thread slot t
                      int* __restrict__ punit)   // (l,t) -> unit u
{
    __shared__ int keys[NW];
    const int l = blockIdx.x;
    const int u = threadIdx.x;

    u64 c = 0;
    #pragma unroll
    for (int j = 0; j < NK; ++j)
        c += 1ull << ((edge_idx[(l * NW + u) * NK + j] & 7) * 8);

    int best_g = 0, best_v = -1;
    #pragma unroll
    for (int g = 0; g < 8; ++g) {
        const int v = (int)((c >> (g * 8)) & 0xFF);
        if (v > best_v) { best_v = v; best_g = g; }
    }
    keys[u] = best_g * NW + u;       // unique key, ordered by peak group
    __syncthreads();

    const int r = u & 7;
    const int myk = keys[u];
    int rank = 0;
    #pragma unroll
    for (int j = 0; j < 32; ++j)
        rank += (keys[8 * j + r] < myk) ? 1 : 0;

    const int o = (rank + 4 * r) & 31;   // latin deal across octets
    const int t = o * 8 + r;             // octet position = residue class
    t_of[l * NW + u]  = t;
    punit[l * NW + t] = u;
}

// ---- P2: emit idxb/wpk in THREAD order with remapped feature ids, ----
// ---- bank-group counting sort + spaced-2 rotation (R15, verified). ----
template <bool PERM>
__global__ __launch_bounds__(256)
void emit_kernel(const float* __restrict__ weights,
                 const int* __restrict__ edge_idx,
                 const int* __restrict__ t_of,
                 const int* __restrict__ punit,
                 int* __restrict__ idxb,
                 unsigned* __restrict__ wpk)
{
    const int l = blockIdx.x;
    const int t = threadIdx.x;
    const int u = PERM ? punit[l * NW + t] : t;
    const int srcbase = (l * NW + u) * NK;
    const int dstbase = (l * NW + t) * NK;
    const int lane = t & 63;

    int   idxv[NK];
    float wv[NK];
    #pragma unroll
    for (int j = 0; j < NK; ++j) {
        int ix = edge_idx[srcbase + j];
        if (PERM && ix >= NIN) {            // remap to thread-slot feature id
            const int f  = ix - NIN;
            const int ls = f >> 8;          // NW == 256
            const int us = f & 255;
            ix = NIN + (ls << 8) + t_of[ls * NW + us];
        }
        idxv[j] = ix;
        wv[j]   = weights[srcbase + j];
    }

    // counting sort by bank group (idx&7), 8x8-bit packed counters
    u64 cntp = 0;
    #pragma unroll
    for (int j = 0; j < NK; ++j)
        cntp += 1ull << ((idxv[j] & 7) * 8);

    u64 x = cntp;                 // per-byte inclusive prefix sum
    x += x << 8;
    x += x << 16;
    x += x << 32;
    u64 cur = x << 8;             // exclusive

    // spaced-2 rotation (R15-verified best oblivious slot coloring)
    const int rot = (2 * (lane & 7) + ((lane >> 3) & 7)) & 15;
    #pragma unroll
    for (int j = 0; j < NK; ++j) {
        const int g   = idxv[j] & 7;
        const int pos = (int)((cur >> (g * 8)) & 0xFF);   // unique 0..15
        cur += 1ull << (g * 8);
        const int slot = (pos + rot) & 15;
        idxb[dstbase + slot] = idxv[j] << 4;
        wpk [dstbase + slot] = pk16(wv[j], wv[j]);
    }
}

extern "C" void kernel_launch(void* const* d_in, const int* in_sizes, int n_in,
                              void* d_out, int out_size, void* d_ws, size_t ws_size,
                              hipStream_t stream)
{
    const float* inputs   = (const float*)d_in[0];
    const float* weights  = (const float*)d_in[1];
    const float* biases   = (const float*)d_in[2];
    const int*   edge_idx = (const int*)d_in[3];
    float* out = (float*)d_out;

    dim3 grid(NB / RPB);   // 2048
    dim3 block(NW);        // 256

    const size_t sz_idxb  = (size_t)NPARAM * 4;        // 128 KB
    const size_t sz_wpk   = (size_t)NPARAM * 4;        // 128 KB
    const size_t sz_map   = (size_t)NL * NW * 4;       // 8 KB each
    const size_t need_basic = sz_idxb + sz_wpk;               // 256 KB
    const size_t need_full  = need_basic + 2 * sz_map;        // 272 KB

    if (ws_size >= need_full) {
        int*      idxb  = (int*)d_ws;
        unsigned* wpk   = (unsigned*)((char*)d_ws + sz_idxb);
        int*      t_of  = (int*)((char*)d_ws + need_basic);
        int*      punit = (int*)((char*)d_ws + need_basic + sz_map);
        partition_kernel<<<NL, NW, 0, stream>>>(edge_idx, t_of, punit);
        emit_kernel<true><<<NL, NW, 0, stream>>>(weights, edge_idx,
                                                 t_of, punit, idxb, wpk);
        ffn_gather_kernel<true, true><<<grid, block, 0, stream>>>(
            inputs, weights, biases, edge_idx, idxb, wpk, punit, out);
    } else if (ws_size >= need_basic) {
        int*      idxb = (int*)d_ws;
        unsigned* wpk  = (unsigned*)((char*)d_ws + sz_idxb);
        emit_kernel<false><<<NL, NW, 0, stream>>>(weights, edge_idx,
                                                  nullptr, nullptr, idxb, wpk);
        ffn_gather_kernel<true, false><<<grid, block, 0, stream>>>(
            inputs, weights, biases, edge_idx, idxb, wpk, nullptr, out);
    } else {
        ffn_gather_kernel<false, false><<<grid, block, 0, stream>>>(
            inputs, weights, biases, edge_idx, nullptr, nullptr, nullptr, out);
    }
}

// Round 6
// 144.089 us; speedup vs baseline: 1.0390x; 1.0149x over previous
//
#include <hip/hip_runtime.h>
#include <hip/hip_bf16.h>
#include <hip/hip_fp16.h>

// Sparse gather-FFN, DS-pipe bound. Verified model: per CU, wave
// ds_read_b128 x 12cyc issue + conflict cycles (SQ_LDS_BANK_CONFLICT/256
// /2.4GHz). R15 (sort idx&7 + spaced-2 rot): 1.494e7 conf, main 67us =
// 41(issue)+24(conf)+2. R16 per-lane flatten: 1.33e7 (-11% only).
// R17 octet-demand partition: 1.52e7 (NULL). Conclusion: &7-granular
// levers are exhausted; data fits a 64-bank (group = idx&15, 16-lane
// phase) model where all &7 manipulation is invisible, and the &15
// demand-variance floor (~6 cyc/instr) needs replication LDS can't hold.
// R18 pivot: attack the ISSUE FLOOR instead. Layer 0 is uniformly
// input-gathers (idx<128, no divergence): pre-pack inputs to a global
// f16 mirror gin[octet][feature] (16B entries, same layout as LDS) and
// serve layer 0 via global_load_dwordx4 from L1 (4KB/block resident).
// -12.5% DS instrs and conflicts on an idle pipe; layer-0 also stops
// needing the initial staging barrier. Sort key idx&7 -> idx&15 (same
// R15 rotation; equivalent-or-better under both bank hypotheses) as the
// free discriminator: conflicts ~1.3e7 -> 32-bank model, <=1.1e7 ->
// 64-bank model (then next round: &15 pack+color).
// Predicted: main 71 -> 57-62us, conflicts 1.52e7 -> 1.1-1.35e7.
// (R19 resubmit: R18 never ran - GPUAcquisitionTimeout. No data, no change.)

#define NB   32768
#define NIN  128
#define NL   8
#define NW   256
#define NK   16
#define RPB  16                       // rows per block = 2 octets x 8
#define STORED (NIN + (NL - 1) * NW)  // 1920 features per group
#define NPARAM (NL * NW * NK)         // 32768 (l,u,k) entries
#define NOCT (NB / 8)                 // 4096 row-octets

typedef __fp16 fp16v2 __attribute__((ext_vector_type(2)));
typedef unsigned long long u64;

__device__ __forceinline__ unsigned pk16(float a, float b) {
    fp16v2 p = __builtin_amdgcn_cvt_pkrtz(a, b);   // v_cvt_pkrtz_f16_f32
    return __builtin_bit_cast(unsigned, p);
}

__device__ __forceinline__ __half2 as_h2(unsigned u) {
    return __builtin_bit_cast(__half2, u);
}

__device__ __forceinline__ float fast_sigmoid(float x) {
    return __builtin_amdgcn_rcpf(1.0f + __expf(-x));
}

// 8 row-MACs from one 16B packed-f16 word: 4x v_pk_fma_f16
__device__ __forceinline__ void fma_feat(__half2 acc[4], __half2 w2, uint4 p) {
    acc[0] = __hfma2(as_h2(p.x), w2, acc[0]);
    acc[1] = __hfma2(as_h2(p.y), w2, acc[1]);
    acc[2] = __hfma2(as_h2(p.z), w2, acc[2]);
    acc[3] = __hfma2(as_h2(p.w), w2, acc[3]);
}

template <bool PRE, bool G0>
__global__ __launch_bounds__(256, 2)
void ffn_gather_kernel(const float* __restrict__ inputs,
                       const float* __restrict__ weights,
                       const float* __restrict__ biases,
                       const int*   __restrict__ edge_idx,
                       const int*   __restrict__ idxb,   // pre-scaled byte offs
                       const unsigned* __restrict__ wpk, // packed (w,w) f16
                       const uint4* __restrict__ gin,    // packed global inputs
                       float* __restrict__ out)
{
    __shared__ uint4 valsA[STORED];   // group A: rows row0..row0+7
    __shared__ uint4 valsB[STORED];   // group B: rows row0+8..row0+15

    const int t = threadIdx.x;                       // 0..255, unit id
    const long long row0 = (long long)blockIdx.x * RPB;
    const char* vbaseA = (const char*)valsA;
    const char* vbaseB = (const char*)valsB;

    // ---- stage 128 input features x 16 rows: t<128 -> A, t>=128 -> B ----
    // (later layers still gather idx<128 from LDS; staying identical)
    {
        const int f = t & 127;
        const long long r0 = row0 + ((t >> 7) << 3);   // +0 (A) or +8 (B)
        float v[8];
        #pragma unroll
        for (int r = 0; r < 8; ++r) v[r] = inputs[(r0 + r) * NIN + f];
        uint4 p;
        p.x = pk16(v[0], v[1]);
        p.y = pk16(v[2], v[3]);
        p.z = pk16(v[4], v[5]);
        p.w = pk16(v[6], v[7]);
        if (t < NIN) valsA[f] = p; else valsB[f] = p;
    }

    if constexpr (G0) {
        // ---- layer 0 entirely from the global mirror (no LDS reads, so
        // the staging barrier is deferred behind this compute) ----
        const char* gA = (const char*)(gin + (size_t)(2 * blockIdx.x)     * NIN);
        const char* gB = (const char*)(gin + (size_t)(2 * blockIdx.x + 1) * NIN);
        const int base = t * NK;                       // l == 0
        const float b = biases[t];
        __half2 accA[4], accB[4];
        const __half2 bb = __float2half2_rn(b);
        #pragma unroll
        for (int j = 0; j < 4; ++j) { accA[j] = bb; accB[j] = bb; }

        #pragma unroll
        for (int kk = 0; kk < NK / 4; ++kk) {
            const int4 o4 = ((const int4*)(idxb + base))[kk];   // < 2048
            const uint4 wp = ((const uint4*)(wpk + base))[kk];
            const __half2 w0 = as_h2(wp.x), w1 = as_h2(wp.y);
            const __half2 w2 = as_h2(wp.z), w3 = as_h2(wp.w);
            const uint4 a0 = *(const uint4*)(gA + o4.x);
            const uint4 b0 = *(const uint4*)(gB + o4.x);
            const uint4 a1 = *(const uint4*)(gA + o4.y);
            const uint4 b1 = *(const uint4*)(gB + o4.y);
            const uint4 a2 = *(const uint4*)(gA + o4.z);
            const uint4 b2 = *(const uint4*)(gB + o4.z);
            const uint4 a3 = *(const uint4*)(gA + o4.w);
            const uint4 b3 = *(const uint4*)(gB + o4.w);
            fma_feat(accA, w0, a0);
            fma_feat(accB, w0, b0);
            fma_feat(accA, w1, a1);
            fma_feat(accB, w1, b1);
            fma_feat(accA, w2, a2);
            fma_feat(accB, w2, b2);
            fma_feat(accA, w3, a3);
            fma_feat(accB, w3, b3);
        }

        float sA[8], sB[8];
        #pragma unroll
        for (int j = 0; j < 4; ++j) {
            sA[2 * j + 0] = fast_sigmoid(__low2float(accA[j]));
            sA[2 * j + 1] = fast_sigmoid(__high2float(accA[j]));
            sB[2 * j + 0] = fast_sigmoid(__low2float(accB[j]));
            sB[2 * j + 1] = fast_sigmoid(__high2float(accB[j]));
        }
        uint4 pA, pB;
        pA.x = pk16(sA[0], sA[1]); pA.y = pk16(sA[2], sA[3]);
        pA.z = pk16(sA[4], sA[5]); pA.w = pk16(sA[6], sA[7]);
        pB.x = pk16(sB[0], sB[1]); pB.y = pk16(sB[2], sB[3]);
        pB.z = pk16(sB[4], sB[5]); pB.w = pk16(sB[6], sB[7]);
        valsA[NIN + t] = pA;
        valsB[NIN + t] = pB;
        __syncthreads();   // ONE barrier covers staging + act0 writes
    } else {
        __syncthreads();
    }

    // ---- layers (from 1 if layer 0 went global) ----
    #pragma unroll
    for (int l = G0 ? 1 : 0; l < NL; ++l) {
        const int base = (l * NW + t) * NK;

        const float b = biases[l * NW + t];
        __half2 accA[4], accB[4];
        const __half2 bb = __float2half2_rn(b);
        #pragma unroll
        for (int j = 0; j < 4; ++j) { accA[j] = bb; accB[j] = bb; }

        #pragma unroll
        for (int kk = 0; kk < NK / 4; ++kk) {
            int4 o4;          // byte offsets into vals (shared by A and B!)
            __half2 w0, w1, w2, w3;
            if (PRE) {
                o4 = ((const int4*)(idxb + base))[kk];
                uint4 wp = ((const uint4*)(wpk + base))[kk];
                w0 = as_h2(wp.x); w1 = as_h2(wp.y);
                w2 = as_h2(wp.z); w3 = as_h2(wp.w);
            } else {
                int4 i4 = ((const int4*)(edge_idx + base))[kk];
                o4.x = i4.x << 4; o4.y = i4.y << 4;
                o4.z = i4.z << 4; o4.w = i4.w << 4;
                float4 w4 = ((const float4*)(weights + base))[kk];
                w0 = __float2half2_rn(w4.x);
                w1 = __float2half2_rn(w4.y);
                w2 = __float2half2_rn(w4.z);
                w3 = __float2half2_rn(w4.w);
            }
            // 8 independent gathers (two per feature, groups A+B)
            const uint4 a0 = *(const uint4*)(vbaseA + o4.x);
            const uint4 b0 = *(const uint4*)(vbaseB + o4.x);
            const uint4 a1 = *(const uint4*)(vbaseA + o4.y);
            const uint4 b1 = *(const uint4*)(vbaseB + o4.y);
            const uint4 a2 = *(const uint4*)(vbaseA + o4.z);
            const uint4 b2 = *(const uint4*)(vbaseB + o4.z);
            const uint4 a3 = *(const uint4*)(vbaseA + o4.w);
            const uint4 b3 = *(const uint4*)(vbaseB + o4.w);
            fma_feat(accA, w0, a0);
            fma_feat(accB, w0, b0);
            fma_feat(accA, w1, a1);
            fma_feat(accB, w1, b1);
            fma_feat(accA, w2, a2);
            fma_feat(accB, w2, b2);
            fma_feat(accA, w3, a3);
            fma_feat(accB, w3, b3);
        }

        float sA[8], sB[8];
        #pragma unroll
        for (int j = 0; j < 4; ++j) {
            sA[2 * j + 0] = fast_sigmoid(__low2float(accA[j]));
            sA[2 * j + 1] = fast_sigmoid(__high2float(accA[j]));
            sB[2 * j + 0] = fast_sigmoid(__low2float(accB[j]));
            sB[2 * j + 1] = fast_sigmoid(__high2float(accB[j]));
        }

        if (l < NL - 1) {
            uint4 pA, pB;
            pA.x = pk16(sA[0], sA[1]); pA.y = pk16(sA[2], sA[3]);
            pA.z = pk16(sA[4], sA[5]); pA.w = pk16(sA[6], sA[7]);
            pB.x = pk16(sB[0], sB[1]); pB.y = pk16(sB[2], sB[3]);
            pB.z = pk16(sB[4], sB[5]); pB.w = pk16(sB[6], sB[7]);
            valsA[NIN + l * NW + t] = pA;
            valsB[NIN + l * NW + t] = pB;
            __syncthreads();           // ONE barrier per 16 rows per layer
        } else {
            #pragma unroll
            for (int r = 0; r < 8; ++r) {
                out[(row0 + r) * NW + t]     = sA[r];
                out[(row0 + 8 + r) * NW + t] = sB[r];
            }
        }
    }
}

// ---- prepass A: pack inputs to global mirror gin[octet][feature] ----
// 16B entry = 8 rows f16, identical layout/rounding to the LDS staging.
__global__ __launch_bounds__(256)
void pack_inputs_kernel(const float* __restrict__ inputs,
                        uint4* __restrict__ gin)
{
    const int tid = blockIdx.x * 256 + threadIdx.x;  // 0..524287
    const int oc = tid >> 7;                         // octet 0..4095
    const int f  = tid & 127;                        // feature
    float v[8];
    #pragma unroll
    for (int r = 0; r < 8; ++r)
        v[r] = inputs[(size_t)(oc * 8 + r) * NIN + f];
    uint4 p;
    p.x = pk16(v[0], v[1]);
    p.y = pk16(v[2], v[3]);
    p.z = pk16(v[4], v[5]);
    p.w = pk16(v[6], v[7]);
    gin[(size_t)oc * NIN + f] = p;
}

// ---- prepass B: byte-offset indices + packed (w,w) f16 weights, ----
// k-slots counting-sorted by bank group idx&15 (64-bank hypothesis;
// refines the &7 sort so it is never worse under the 32-bank model),
// then R15's verified spaced-2 rotation.
__global__ __launch_bounds__(256)
void emit_kernel(const float* __restrict__ weights,
                 const int* __restrict__ edge_idx,
                 int* __restrict__ idxb,
                 unsigned* __restrict__ wpk)
{
    const int tgid = blockIdx.x * 256 + threadIdx.x; // 0..2047: unit (l,u)
    const int lane = tgid & 63;                      // main-kernel wave lane
    const int base = tgid * NK;

    int   idxv[NK];
    float wv[NK];
    #pragma unroll
    for (int j = 0; j < NK; ++j) {
        idxv[j] = edge_idx[base + j];
        wv[j]   = weights[base + j];
    }

    // counting sort by g16 = idx & 15: groups 0-7 in cA bytes, 8-15 in cB
    u64 cA = 0, cB = 0;
    #pragma unroll
    for (int j = 0; j < NK; ++j) {
        const int g = idxv[j] & 15;
        const u64 inc = 1ull << ((g & 7) * 8);
        if (g < 8) cA += inc; else cB += inc;
    }
    u64 xA = cA; xA += xA << 8; xA += xA << 16; xA += xA << 32;
    u64 xB = cB; xB += xB << 8; xB += xB << 16; xB += xB << 32;
    const int totA = (int)((xA >> 56) & 0xFF);
    u64 curA = xA << 8, curB = xB << 8;      // exclusive prefix sums

    const int rot = (2 * (lane & 7) + ((lane >> 3) & 7)) & 15;
    #pragma unroll
    for (int j = 0; j < NK; ++j) {
        const int g  = idxv[j] & 15;
        const int gb = (g & 7) * 8;
        int pos;
        if (g < 8) { pos = (int)((curA >> gb) & 0xFF);        curA += 1ull << gb; }
        else       { pos = totA + (int)((curB >> gb) & 0xFF); curB += 1ull << gb; }
        const int slot = (pos + rot) & 15;   // unique 0..15
        idxb[base + slot] = idxv[j] << 4;
        wpk [base + slot] = pk16(wv[j], wv[j]);
    }
}

extern "C" void kernel_launch(void* const* d_in, const int* in_sizes, int n_in,
                              void* d_out, int out_size, void* d_ws, size_t ws_size,
                              hipStream_t stream)
{
    const float* inputs   = (const float*)d_in[0];
    const float* weights  = (const float*)d_in[1];
    const float* biases   = (const float*)d_in[2];
    const int*   edge_idx = (const int*)d_in[3];
    float* out = (float*)d_out;

    dim3 grid(NB / RPB);   // 2048
    dim3 block(NW);        // 256

    const size_t sz_tab = (size_t)NPARAM * 4 * 2;        // 256 KB
    const size_t sz_gin = (size_t)NOCT * NIN * 16;       // 8 MB

    if (ws_size >= sz_tab + sz_gin) {
        int*      idxb = (int*)d_ws;
        unsigned* wpk  = (unsigned*)((char*)d_ws + (size_t)NPARAM * 4);
        uint4*    gin  = (uint4*)((char*)d_ws + sz_tab);
        pack_inputs_kernel<<<NOCT * NIN / 256, 256, 0, stream>>>(inputs, gin);
        emit_kernel<<<NL * NW / 256, 256, 0, stream>>>(weights, edge_idx,
                                                       idxb, wpk);
        ffn_gather_kernel<true, true><<<grid, block, 0, stream>>>(
            inputs, weights, biases, edge_idx, idxb, wpk, gin, out);
    } else if (ws_size >= sz_tab) {
        int*      idxb = (int*)d_ws;
        unsigned* wpk  = (unsigned*)((char*)d_ws + (size_t)NPARAM * 4);
        emit_kernel<<<NL * NW / 256, 256, 0, stream>>>(weights, edge_idx,
                                                       idxb, wpk);
        ffn_gather_kernel<true, false><<<grid, block, 0, stream>>>(
            inputs, weights, biases, edge_idx, idxb, wpk, nullptr, out);
    } else {
        ffn_gather_kernel<false, false><<<grid, block, 0, stream>>>(
            inputs, weights, biases, edge_idx, nullptr, nullptr, nullptr, out);
    }
}